// Round 1
// baseline (85459.576 us; speedup 1.0000x reference)
//
#include <hip/hip_runtime.h>
#include <math.h>

// Problem constants
#define BB 8
#define CC 2048
#define DD 64
#define LL 3
#define HH 4
#define DHH 16

// ---------------- exact GELU via A&S 7.1.26 erf (|err| < 1.5e-7) ----------------
__device__ __forceinline__ float gelu_f(float x) {
    float z  = 0.70710678118654752f * x;
    float az = fabsf(z);
    float t  = __builtin_amdgcn_rcpf(fmaf(0.3275911f, az, 1.0f));
    float p  = t * fmaf(t, fmaf(t, fmaf(t, fmaf(t, 1.061405429f, -1.453152027f),
                                        1.421413741f), -0.284496736f), 0.254829592f);
    float e  = __expf(-z * z);
    float r  = p * e;                                // erfc(|z|)
    float phi = (x >= 0.0f) ? fmaf(-0.5f, r, 1.0f) : 0.5f * r;
    return x * phi;
}

__device__ __forceinline__ float wave_sum64(float v) {
    #pragma unroll
    for (int off = 32; off; off >>= 1) v += __shfl_xor(v, off, 64);
    return v;
}

// ---------------- binding encoder: h = role * gelu(log1p(max(x,0)) * filler_w) ----------------
__global__ __launch_bounds__(256) void k_binding(const float* __restrict__ x,
                                                 const float* __restrict__ role,
                                                 const float* __restrict__ fw,
                                                 float* __restrict__ h) {
    int idx = blockIdx.x * 256 + threadIdx.x;        // B*C*D = 1048576
    int d  = idx & 63;
    int bc = idx >> 6;
    float xl = log1pf(fmaxf(x[bc], 0.0f));
    float f  = gelu_f(xl * fw[d]);
    h[idx] = role[(bc & (CC - 1)) * DD + d] * f;
}

// ---------------- QKV projection + qp (A=qp+b1) and kp precompute ----------------
__global__ __launch_bounds__(256) void k_qkv(const float* __restrict__ h,
                                             const float* __restrict__ qw, const float* __restrict__ qb,
                                             const float* __restrict__ kw, const float* __restrict__ kb,
                                             const float* __restrict__ vw, const float* __restrict__ vb,
                                             const float* __restrict__ w1, const float* __restrict__ b1,
                                             float* __restrict__ Q, float* __restrict__ K,
                                             float* __restrict__ V, float* __restrict__ A,
                                             float* __restrict__ KP) {
    __shared__ float hrow[4][64];
    __shared__ float qrow[4][64];
    __shared__ float krow[4][64];
    int r  = threadIdx.x >> 6;
    int j  = threadIdx.x & 63;
    int bc = blockIdx.x * 4 + r;                     // 0..16383
    hrow[r][j] = h[(size_t)bc * 64 + j];
    __syncthreads();
    float aq = qb[j], ak = kb[j], av = vb[j];
    const float* hr = hrow[r];
    #pragma unroll
    for (int i = 0; i < 64; ++i) {
        float hv = hr[i];
        aq = fmaf(hv, qw[j * 64 + i], aq);
        ak = fmaf(hv, kw[j * 64 + i], ak);
        av = fmaf(hv, vw[j * 64 + i], av);
    }
    int head = j >> 4, dh = j & 15;
    int b = bc >> 11, c = bc & (CC - 1);
    size_t o = ((size_t)(b * HH + head) * CC + c) * DHH + dh;
    Q[o] = aq; K[o] = ak; V[o] = av;
    qrow[r][j] = aq; krow[r][j] = ak;
    __syncthreads();
    float aA = b1[dh], akp = 0.0f;
    #pragma unroll
    for (int i = 0; i < 16; ++i) {
        aA  = fmaf(qrow[r][head * 16 + i], w1[dh * 48 + i],      aA);
        akp = fmaf(krow[r][head * 16 + i], w1[dh * 48 + 16 + i], akp);
    }
    A[o] = aA; KP[o] = akp;
}

// ---------------- attention with MLP scores, key-split partials ----------------
// grid: qc(8) x bh(32) x ks(4) = 1024 blocks, 256 threads (1 query/thread)
__global__ __launch_bounds__(256) void k_attn(const float* __restrict__ Q, const float* __restrict__ K,
                                              const float* __restrict__ V, const float* __restrict__ A,
                                              const float* __restrict__ KP,
                                              const float* __restrict__ w1, const float* __restrict__ w2,
                                              float* __restrict__ PACC, float* __restrict__ PS) {
    __shared__ __attribute__((aligned(16))) float Wl[16][16];
    __shared__ float w2s[16];
    __shared__ __attribute__((aligned(16))) float kt[32][16];
    __shared__ __attribute__((aligned(16))) float vt[32][16];
    __shared__ __attribute__((aligned(16))) float kpt[32][16];

    int tid = threadIdx.x;
    int qc = blockIdx.x & 7;
    int bh = (blockIdx.x >> 3) & 31;
    int ks = blockIdx.x >> 8;

    Wl[tid >> 4][tid & 15] = w1[(tid >> 4) * 48 + 32 + (tid & 15)];
    if (tid < 16) w2s[tid] = w2[tid] * 0.25f;        // fold 1/sqrt(16); b2 is softmax-invariant

    size_t base = (size_t)bh * (CC * DHH);
    int cq = qc * 256 + tid;

    float qv[16], Aq[16];
    {
        const float4* q4 = (const float4*)(Q + base + (size_t)cq * 16);
        const float4* a4 = (const float4*)(A + base + (size_t)cq * 16);
        #pragma unroll
        for (int i = 0; i < 4; ++i) {
            float4 a = q4[i], b = a4[i];
            qv[4*i] = a.x; qv[4*i+1] = a.y; qv[4*i+2] = a.z; qv[4*i+3] = a.w;
            Aq[4*i] = b.x; Aq[4*i+1] = b.y; Aq[4*i+2] = b.z; Aq[4*i+3] = b.w;
        }
    }
    float acc[16];
    #pragma unroll
    for (int i = 0; i < 16; ++i) acc[i] = 0.0f;
    float ssum = 0.0f;

    int t_beg = ks * 512, t_end = t_beg + 512;
    for (int t0 = t_beg; t0 < t_end; t0 += 32) {
        __syncthreads();                              // protect LDS from prior iter readers
        {
            const float4* ksrc = (const float4*)(K  + base + (size_t)t0 * 16);
            const float4* vsrc = (const float4*)(V  + base + (size_t)t0 * 16);
            const float4* psrc = (const float4*)(KP + base + (size_t)t0 * 16);
            for (int u = tid; u < 384; u += 256) {
                int a = u >> 7, off = u & 127;
                float4 val = (a == 0) ? ksrc[off] : (a == 1) ? vsrc[off] : psrc[off];
                float4* dst = (a == 0) ? (float4*)kt : (a == 1) ? (float4*)vt : (float4*)kpt;
                dst[off] = val;
            }
        }
        __syncthreads();

        #pragma unroll 1
        for (int kk = 0; kk < 32; kk += 2) {
            float p0[16], p1[16];
            #pragma unroll
            for (int i = 0; i < 16; ++i) {
                p0[i] = qv[i] * kt[kk][i];
                p1[i] = qv[i] * kt[kk + 1][i];
            }
            float s0 = 0.0f, s1 = 0.0f;
            #pragma unroll
            for (int j = 0; j < 16; ++j) {
                float r0 = Aq[j] + kpt[kk][j];
                float r1 = Aq[j] + kpt[kk + 1][j];
                #pragma unroll
                for (int i = 0; i < 16; ++i) {
                    float w = Wl[j][i];
                    r0 = fmaf(w, p0[i], r0);
                    r1 = fmaf(w, p1[i], r1);
                }
                s0 = fmaf(w2s[j], gelu_f(r0), s0);
                s1 = fmaf(w2s[j], gelu_f(r1), s1);
            }
            // scores bounded (|s| < ~8): max-free online softmax is safe in fp32
            float e0 = __expf(s0), e1 = __expf(s1);
            ssum += e0 + e1;
            #pragma unroll
            for (int i = 0; i < 16; ++i)
                acc[i] = fmaf(e0, vt[kk][i], fmaf(e1, vt[kk + 1][i], acc[i]));
        }
    }

    float* pa = PACC + ((size_t)(ks * 32 + bh) * CC + cq) * 16;
    #pragma unroll
    for (int i = 0; i < 4; ++i) {
        float4 o;
        o.x = acc[4*i]; o.y = acc[4*i+1]; o.z = acc[4*i+2]; o.w = acc[4*i+3];
        ((float4*)pa)[i] = o;
    }
    PS[(size_t)(ks * 32 + bh) * CC + cq] = ssum;
}

// ---------------- combine key-split partials -> attn [B,C,D] ----------------
__global__ __launch_bounds__(256) void k_attn_combine(const float* __restrict__ PACC,
                                                      const float* __restrict__ PS,
                                                      float* __restrict__ AT) {
    int idx = blockIdx.x * 256 + threadIdx.x;        // 65536 queries
    int bh = idx >> 11, cq = idx & (CC - 1);
    float acc[16];
    #pragma unroll
    for (int i = 0; i < 16; ++i) acc[i] = 0.0f;
    float ssum = 0.0f;
    #pragma unroll
    for (int s = 0; s < 4; ++s) {
        const float4* pa = (const float4*)(PACC + ((size_t)(s * 32 + bh) * CC + cq) * 16);
        ssum += PS[(size_t)(s * 32 + bh) * CC + cq];
        #pragma unroll
        for (int i = 0; i < 4; ++i) {
            float4 v = pa[i];
            acc[4*i] += v.x; acc[4*i+1] += v.y; acc[4*i+2] += v.z; acc[4*i+3] += v.w;
        }
    }
    float inv = 1.0f / ssum;
    int b = bh >> 2, hh = bh & 3;
    float* dst = AT + ((size_t)(b * CC + cq)) * DD + hh * 16;
    #pragma unroll
    for (int i = 0; i < 4; ++i) {
        float4 o;
        o.x = acc[4*i]*inv; o.y = acc[4*i+1]*inv; o.z = acc[4*i+2]*inv; o.w = acc[4*i+3]*inv;
        ((float4*)dst)[i] = o;
    }
}

// ---------------- out-proj + residual + LN1 (1 wave per row) ----------------
__global__ __launch_bounds__(64) void k_oproj_ln(const float* __restrict__ AT,
                                                 const float* __restrict__ ow, const float* __restrict__ ob,
                                                 const float* __restrict__ g, const float* __restrict__ be,
                                                 float* __restrict__ h) {
    int bc = blockIdx.x;
    int j  = threadIdx.x;
    __shared__ float ar[64];
    ar[j] = AT[(size_t)bc * 64 + j];
    __syncthreads();
    float o = ob[j];
    #pragma unroll
    for (int i = 0; i < 64; ++i) o = fmaf(ar[i], ow[j * 64 + i], o);
    float t = h[(size_t)bc * 64 + j] + o;
    float m  = wave_sum64(t) * (1.0f / 64.0f);
    float dv = t - m;
    float vv = wave_sum64(dv * dv) * (1.0f / 64.0f);
    float r  = __builtin_amdgcn_rsqf(vv + 1e-5f);
    h[(size_t)bc * 64 + j] = fmaf(dv * r, g[j], be[j]);
}

// ---------------- FFN (64->256 gelu ->64) + residual + LN2 ----------------
__global__ __launch_bounds__(256) void k_ffn_ln(const float* __restrict__ f1w, const float* __restrict__ f1b,
                                                const float* __restrict__ f2w, const float* __restrict__ f2b,
                                                const float* __restrict__ g, const float* __restrict__ be,
                                                float* __restrict__ h) {
    int bc = blockIdx.x;
    int t  = threadIdx.x;
    __shared__ float hr[64];
    __shared__ float u[256];
    __shared__ float parts[4][64];
    if (t < 64) hr[t] = h[(size_t)bc * 64 + t];
    __syncthreads();
    float a = f1b[t];
    #pragma unroll
    for (int i = 0; i < 64; ++i) a = fmaf(hr[i], f1w[t * 64 + i], a);
    u[t] = gelu_f(a);
    __syncthreads();
    int j = t & 63, part = t >> 6;
    float p = 0.0f;
    #pragma unroll
    for (int i = 0; i < 64; ++i) p = fmaf(u[part * 64 + i], f2w[j * 256 + part * 64 + i], p);
    parts[part][j] = p;
    __syncthreads();
    if (t < 64) {
        float o = f2b[t] + parts[0][t] + parts[1][t] + parts[2][t] + parts[3][t];
        float x = hr[t] + o;
        float m  = wave_sum64(x) * (1.0f / 64.0f);
        float dv = x - m;
        float vv = wave_sum64(dv * dv) * (1.0f / 64.0f);
        float r  = __builtin_amdgcn_rsqf(vv + 1e-5f);
        h[(size_t)bc * 64 + t] = fmaf(dv * r, g[t], be[t]);
    }
}

// ---------------- task-query readout ----------------
__global__ __launch_bounds__(256) void k_readout(const float* __restrict__ h,
                                                 const float* __restrict__ tq,
                                                 const float* __restrict__ hw, const float* __restrict__ hb,
                                                 float* __restrict__ out) {
    int b = blockIdx.x;
    int t = threadIdx.x;
    __shared__ float ebuf[2048];
    __shared__ float tqs[64];
    __shared__ float sred[256];
    __shared__ float red[4][64];
    if (t < 64) tqs[t] = tq[t];
    __syncthreads();
    float ss = 0.0f;
    for (int c = t; c < CC; c += 256) {
        const float* hrow = h + ((size_t)b * CC + c) * 64;
        float s = 0.0f;
        #pragma unroll
        for (int d = 0; d < 64; ++d) s = fmaf(hrow[d], tqs[d], s);
        float e = __expf(s * 0.125f);                 // scores ~ +-0.1: max-free safe
        ebuf[c] = e; ss += e;
    }
    sred[t] = ss;
    __syncthreads();
    for (int o = 128; o; o >>= 1) {
        if (t < o) sred[t] += sred[t + o];
        __syncthreads();
    }
    float inv = 1.0f / sred[0];
    int d = t & 63, ch = t >> 6;
    float p = 0.0f;
    for (int c = ch * 512; c < ch * 512 + 512; ++c)
        p = fmaf(ebuf[c], h[((size_t)b * CC + c) * 64 + d], p);
    red[ch][d] = p;
    __syncthreads();
    if (t < 64) red[0][t] = (red[0][t] + red[1][t] + red[2][t] + red[3][t]) * inv;
    __syncthreads();
    if (t < 10) {
        float o = hb[t];
        #pragma unroll
        for (int d2 = 0; d2 < 64; ++d2) o = fmaf(red[0][d2], hw[t * 64 + d2], o);
        out[b * 10 + t] = o;
    }
}

extern "C" void kernel_launch(void* const* d_in, const int* in_sizes, int n_in,
                              void* d_out, int out_size, void* d_ws, size_t ws_size,
                              hipStream_t stream) {
    (void)in_sizes; (void)n_in; (void)out_size; (void)ws_size;
    const float* x    = (const float*)d_in[0];
    const float* role = (const float*)d_in[1];
    const float* fw   = (const float*)d_in[2];
    const float* qw   = (const float*)d_in[3];
    const float* qb   = (const float*)d_in[4];
    const float* kw   = (const float*)d_in[5];
    const float* kb   = (const float*)d_in[6];
    const float* vw   = (const float*)d_in[7];
    const float* vb   = (const float*)d_in[8];
    const float* w1   = (const float*)d_in[9];
    const float* b1   = (const float*)d_in[10];
    const float* w2   = (const float*)d_in[11];
    // d_in[12] = b2: softmax-shift-invariant, dropped
    const float* ow   = (const float*)d_in[13];
    const float* ob   = (const float*)d_in[14];
    const float* g1   = (const float*)d_in[15];
    const float* be1  = (const float*)d_in[16];
    const float* f1w  = (const float*)d_in[17];
    const float* f1b  = (const float*)d_in[18];
    const float* f2w  = (const float*)d_in[19];
    const float* f2b  = (const float*)d_in[20];
    const float* g2   = (const float*)d_in[21];
    const float* be2  = (const float*)d_in[22];
    const float* tq   = (const float*)d_in[23];
    const float* hw   = (const float*)d_in[24];
    const float* hb   = (const float*)d_in[25];

    float* ws   = (float*)d_ws;
    const size_t M = 1048576;                        // B*C*D
    float* H    = ws;
    float* Q    = ws + 1 * M;
    float* K    = ws + 2 * M;
    float* V    = ws + 3 * M;
    float* Abuf = ws + 4 * M;
    float* KP   = ws + 5 * M;
    float* AT   = ws + 6 * M;
    float* PACC = ws + 7 * M;                        // 4*32*2048*16 = 4M floats
    float* PS   = ws + 11 * M + 262144;              // 4*32*2048

    k_binding<<<4096, 256, 0, stream>>>(x, role, fw, H);
    for (int l = 0; l < LL; ++l) {
        k_qkv<<<4096, 256, 0, stream>>>(H, qw + l * 4096, qb + l * 64, kw + l * 4096, kb + l * 64,
                                        vw + l * 4096, vb + l * 64, w1 + l * 768, b1 + l * 16,
                                        Q, K, V, Abuf, KP);
        k_attn<<<1024, 256, 0, stream>>>(Q, K, V, Abuf, KP, w1 + l * 768, w2 + l * 16, PACC, PS);
        k_attn_combine<<<256, 256, 0, stream>>>(PACC, PS, AT);
        k_oproj_ln<<<16384, 64, 0, stream>>>(AT, ow + l * 4096, ob + l * 64, g1 + l * 64, be1 + l * 64, H);
        k_ffn_ln<<<16384, 256, 0, stream>>>(f1w + l * 16384, f1b + l * 256, f2w + l * 16384,
                                            f2b + l * 64, g2 + l * 64, be2 + l * 64, H);
    }
    k_readout<<<8, 256, 0, stream>>>(H, tq, hw, hb, (float*)d_out);
}

// Round 2
// 7771.666 us; speedup vs baseline: 10.9963x; 10.9963x over previous
//
#include <hip/hip_runtime.h>
#include <math.h>

// Problem constants
#define BB 8
#define CC 2048
#define DD 64
#define LL 3
#define HH 4
#define DHH 16

// ---------------- exact GELU via A&S 7.1.26 erf (|err| < 1.5e-7) ----------------
__device__ __forceinline__ float gelu_f(float x) {
    float z  = 0.70710678118654752f * x;
    float az = fabsf(z);
    float t  = __builtin_amdgcn_rcpf(fmaf(0.3275911f, az, 1.0f));
    float p  = t * fmaf(t, fmaf(t, fmaf(t, fmaf(t, 1.061405429f, -1.453152027f),
                                        1.421413741f), -0.284496736f), 0.254829592f);
    float e  = __expf(-z * z);
    float r  = p * e;                                // erfc(|z|)
    float phi = (x >= 0.0f) ? fmaf(-0.5f, r, 1.0f) : 0.5f * r;
    return x * phi;
}

__device__ __forceinline__ float wave_sum64(float v) {
    #pragma unroll
    for (int off = 32; off; off >>= 1) v += __shfl_xor(v, off, 64);
    return v;
}

// ---------------- binding encoder: h = role * gelu(log1p(max(x,0)) * filler_w) ----------------
__global__ __launch_bounds__(256) void k_binding(const float* __restrict__ x,
                                                 const float* __restrict__ role,
                                                 const float* __restrict__ fw,
                                                 float* __restrict__ h) {
    int idx = blockIdx.x * 256 + threadIdx.x;        // B*C*D = 1048576
    int d  = idx & 63;
    int bc = idx >> 6;
    float xl = log1pf(fmaxf(x[bc], 0.0f));
    float f  = gelu_f(xl * fw[d]);
    h[idx] = role[(bc & (CC - 1)) * DD + d] * f;
}

// ---------------- QKV projection + qp (A=qp+b1) and kp precompute ----------------
__global__ __launch_bounds__(256) void k_qkv(const float* __restrict__ h,
                                             const float* __restrict__ qw, const float* __restrict__ qb,
                                             const float* __restrict__ kw, const float* __restrict__ kb,
                                             const float* __restrict__ vw, const float* __restrict__ vb,
                                             const float* __restrict__ w1, const float* __restrict__ b1,
                                             float* __restrict__ Q, float* __restrict__ K,
                                             float* __restrict__ V, float* __restrict__ A,
                                             float* __restrict__ KP) {
    __shared__ float hrow[4][64];
    __shared__ float qrow[4][64];
    __shared__ float krow[4][64];
    int r  = threadIdx.x >> 6;
    int j  = threadIdx.x & 63;
    int bc = blockIdx.x * 4 + r;                     // 0..16383
    hrow[r][j] = h[(size_t)bc * 64 + j];
    __syncthreads();
    float aq = qb[j], ak = kb[j], av = vb[j];
    const float* hr = hrow[r];
    #pragma unroll
    for (int i = 0; i < 64; ++i) {
        float hv = hr[i];
        aq = fmaf(hv, qw[j * 64 + i], aq);
        ak = fmaf(hv, kw[j * 64 + i], ak);
        av = fmaf(hv, vw[j * 64 + i], av);
    }
    int head = j >> 4, dh = j & 15;
    int b = bc >> 11, c = bc & (CC - 1);
    size_t o = ((size_t)(b * HH + head) * CC + c) * DHH + dh;
    Q[o] = aq; K[o] = ak; V[o] = av;
    qrow[r][j] = aq; krow[r][j] = ak;
    __syncthreads();
    float aA = b1[dh], akp = 0.0f;
    #pragma unroll
    for (int i = 0; i < 16; ++i) {
        aA  = fmaf(qrow[r][head * 16 + i], w1[dh * 48 + i],      aA);
        akp = fmaf(krow[r][head * 16 + i], w1[dh * 48 + 16 + i], akp);
    }
    A[o] = aA; KP[o] = akp;
}

// ---------------- attention with MLP scores, key-split partials ----------------
// grid: qc(8) x bh(32) x ks(4) = 1024 blocks, 256 threads (1 query/thread).
// W1qk/w2 are read via wave-uniform global loads -> s_load/SGPR operands (no LDS,
// no VGPR pressure). Key row pulled to registers once; j-loop is pure-register FMA.
__global__ __launch_bounds__(256, 4) void k_attn(const float* __restrict__ Q, const float* __restrict__ K,
                                                 const float* __restrict__ V, const float* __restrict__ A,
                                                 const float* __restrict__ KP,
                                                 const float* __restrict__ w1g, const float* __restrict__ w2g,
                                                 float* __restrict__ PACC, float* __restrict__ PS) {
    __shared__ __attribute__((aligned(16))) float kt[64][16];
    __shared__ __attribute__((aligned(16))) float vt[64][16];
    __shared__ __attribute__((aligned(16))) float kpt[64][16];

    int tid = threadIdx.x;
    int qc = blockIdx.x & 7;
    int bh = (blockIdx.x >> 3) & 31;
    int ks = blockIdx.x >> 8;

    size_t base = (size_t)bh * (CC * DHH);
    int cq = qc * 256 + tid;

    float qv[16], Aq[16];
    {
        const float4* q4 = (const float4*)(Q + base + (size_t)cq * 16);
        const float4* a4 = (const float4*)(A + base + (size_t)cq * 16);
        #pragma unroll
        for (int i = 0; i < 4; ++i) {
            float4 a = q4[i], b = a4[i];
            qv[4*i] = a.x; qv[4*i+1] = a.y; qv[4*i+2] = a.z; qv[4*i+3] = a.w;
            Aq[4*i] = b.x; Aq[4*i+1] = b.y; Aq[4*i+2] = b.z; Aq[4*i+3] = b.w;
        }
    }
    float acc[16];
    #pragma unroll
    for (int i = 0; i < 16; ++i) acc[i] = 0.0f;
    float ssum = 0.0f;

    const float* wq = w1g + 32;                      // row j: wq[j*48 + i], wave-uniform

    int t_beg = ks * 512;
    #pragma unroll 1
    for (int t0 = t_beg; t0 < t_beg + 512; t0 += 64) {
        __syncthreads();                              // protect LDS from prior iter readers
        ((float4*)kt)[tid]  = ((const float4*)(K  + base + (size_t)t0 * 16))[tid];
        ((float4*)vt)[tid]  = ((const float4*)(V  + base + (size_t)t0 * 16))[tid];
        ((float4*)kpt)[tid] = ((const float4*)(KP + base + (size_t)t0 * 16))[tid];
        __syncthreads();

        #pragma unroll 1
        for (int kk = 0; kk < 64; ++kk) {
            // pull this key's rows into registers (wave-uniform LDS broadcast reads)
            float p[16], kp[16];
            {
                const float4* kr4 = (const float4*)kt[kk];
                const float4* pr4 = (const float4*)kpt[kk];
                #pragma unroll
                for (int i = 0; i < 4; ++i) {
                    float4 a = kr4[i], b = pr4[i];
                    p[4*i]   = qv[4*i]   * a.x;
                    p[4*i+1] = qv[4*i+1] * a.y;
                    p[4*i+2] = qv[4*i+2] * a.z;
                    p[4*i+3] = qv[4*i+3] * a.w;
                    kp[4*i] = b.x; kp[4*i+1] = b.y; kp[4*i+2] = b.z; kp[4*i+3] = b.w;
                }
            }
            float s = 0.0f;
            #pragma unroll 4
            for (int j = 0; j < 16; ++j) {
                float r = Aq[j] + kp[j];
                #pragma unroll
                for (int i = 0; i < 16; ++i)
                    r = fmaf(wq[j * 48 + i], p[i], r);   // SGPR weight operand
                s = fmaf(w2g[j], gelu_f(r), s);
            }
            // scores bounded (|s| < ~8): max-free online softmax is safe in fp32
            float e = __expf(s * 0.25f);              // fold 1/sqrt(16)
            ssum += e;
            const float4* vr4 = (const float4*)vt[kk];
            #pragma unroll
            for (int i = 0; i < 4; ++i) {
                float4 v = vr4[i];
                acc[4*i]   = fmaf(e, v.x, acc[4*i]);
                acc[4*i+1] = fmaf(e, v.y, acc[4*i+1]);
                acc[4*i+2] = fmaf(e, v.z, acc[4*i+2]);
                acc[4*i+3] = fmaf(e, v.w, acc[4*i+3]);
            }
        }
    }

    float* pa = PACC + ((size_t)(ks * 32 + bh) * CC + cq) * 16;
    #pragma unroll
    for (int i = 0; i < 4; ++i) {
        float4 o;
        o.x = acc[4*i]; o.y = acc[4*i+1]; o.z = acc[4*i+2]; o.w = acc[4*i+3];
        ((float4*)pa)[i] = o;
    }
    PS[(size_t)(ks * 32 + bh) * CC + cq] = ssum;
}

// ---------------- combine key-split partials -> attn [B,C,D] ----------------
__global__ __launch_bounds__(256) void k_attn_combine(const float* __restrict__ PACC,
                                                      const float* __restrict__ PS,
                                                      float* __restrict__ AT) {
    int idx = blockIdx.x * 256 + threadIdx.x;        // 65536 queries
    int bh = idx >> 11, cq = idx & (CC - 1);
    float acc[16];
    #pragma unroll
    for (int i = 0; i < 16; ++i) acc[i] = 0.0f;
    float ssum = 0.0f;
    #pragma unroll
    for (int s = 0; s < 4; ++s) {
        const float4* pa = (const float4*)(PACC + ((size_t)(s * 32 + bh) * CC + cq) * 16);
        ssum += PS[(size_t)(s * 32 + bh) * CC + cq];
        #pragma unroll
        for (int i = 0; i < 4; ++i) {
            float4 v = pa[i];
            acc[4*i] += v.x; acc[4*i+1] += v.y; acc[4*i+2] += v.z; acc[4*i+3] += v.w;
        }
    }
    float inv = 1.0f / ssum;
    int b = bh >> 2, hh = bh & 3;
    float* dst = AT + ((size_t)(b * CC + cq)) * DD + hh * 16;
    #pragma unroll
    for (int i = 0; i < 4; ++i) {
        float4 o;
        o.x = acc[4*i]*inv; o.y = acc[4*i+1]*inv; o.z = acc[4*i+2]*inv; o.w = acc[4*i+3]*inv;
        ((float4*)dst)[i] = o;
    }
}

// ---------------- out-proj + residual + LN1 (4 rows per 256-thread block) ----------------
__global__ __launch_bounds__(256) void k_oproj_ln(const float* __restrict__ AT,
                                                  const float* __restrict__ ow, const float* __restrict__ ob,
                                                  const float* __restrict__ g, const float* __restrict__ be,
                                                  float* __restrict__ h) {
    int r  = threadIdx.x >> 6;
    int j  = threadIdx.x & 63;
    int bc = blockIdx.x * 4 + r;
    __shared__ float ar[4][64];
    ar[r][j] = AT[(size_t)bc * 64 + j];
    __syncthreads();
    float o = ob[j];
    #pragma unroll
    for (int i = 0; i < 64; ++i) o = fmaf(ar[r][i], ow[j * 64 + i], o);
    float t = h[(size_t)bc * 64 + j] + o;
    float m  = wave_sum64(t) * (1.0f / 64.0f);
    float dv = t - m;
    float vv = wave_sum64(dv * dv) * (1.0f / 64.0f);
    float rr = __builtin_amdgcn_rsqf(vv + 1e-5f);
    h[(size_t)bc * 64 + j] = fmaf(dv * rr, g[j], be[j]);
}

// ---------------- FFN (64->256 gelu ->64) + residual + LN2 ----------------
__global__ __launch_bounds__(256) void k_ffn_ln(const float* __restrict__ f1w, const float* __restrict__ f1b,
                                                const float* __restrict__ f2w, const float* __restrict__ f2b,
                                                const float* __restrict__ g, const float* __restrict__ be,
                                                float* __restrict__ h) {
    int bc = blockIdx.x;
    int t  = threadIdx.x;
    __shared__ float hr[64];
    __shared__ float u[256];
    __shared__ float parts[4][64];
    if (t < 64) hr[t] = h[(size_t)bc * 64 + t];
    __syncthreads();
    float a = f1b[t];
    #pragma unroll
    for (int i = 0; i < 64; ++i) a = fmaf(hr[i], f1w[t * 64 + i], a);
    u[t] = gelu_f(a);
    __syncthreads();
    int j = t & 63, part = t >> 6;
    float p = 0.0f;
    #pragma unroll
    for (int i = 0; i < 64; ++i) p = fmaf(u[part * 64 + i], f2w[j * 256 + part * 64 + i], p);
    parts[part][j] = p;
    __syncthreads();
    if (t < 64) {
        float o = f2b[t] + parts[0][t] + parts[1][t] + parts[2][t] + parts[3][t];
        float x = hr[t] + o;
        float m  = wave_sum64(x) * (1.0f / 64.0f);
        float dv = x - m;
        float vv = wave_sum64(dv * dv) * (1.0f / 64.0f);
        float r  = __builtin_amdgcn_rsqf(vv + 1e-5f);
        h[(size_t)bc * 64 + t] = fmaf(dv * r, g[t], be[t]);
    }
}

// ---------------- task-query readout ----------------
__global__ __launch_bounds__(256) void k_readout(const float* __restrict__ h,
                                                 const float* __restrict__ tq,
                                                 const float* __restrict__ hw, const float* __restrict__ hb,
                                                 float* __restrict__ out) {
    int b = blockIdx.x;
    int t = threadIdx.x;
    __shared__ float ebuf[2048];
    __shared__ float tqs[64];
    __shared__ float sred[256];
    __shared__ float red[4][64];
    if (t < 64) tqs[t] = tq[t];
    __syncthreads();
    float ss = 0.0f;
    for (int c = t; c < CC; c += 256) {
        const float* hrow = h + ((size_t)b * CC + c) * 64;
        float s = 0.0f;
        #pragma unroll
        for (int d = 0; d < 64; ++d) s = fmaf(hrow[d], tqs[d], s);
        float e = __expf(s * 0.125f);                 // scores ~ +-0.1: max-free safe
        ebuf[c] = e; ss += e;
    }
    sred[t] = ss;
    __syncthreads();
    for (int o = 128; o; o >>= 1) {
        if (t < o) sred[t] += sred[t + o];
        __syncthreads();
    }
    float inv = 1.0f / sred[0];
    int d = t & 63, ch = t >> 6;
    float p = 0.0f;
    for (int c = ch * 512; c < ch * 512 + 512; ++c)
        p = fmaf(ebuf[c], h[((size_t)b * CC + c) * 64 + d], p);
    red[ch][d] = p;
    __syncthreads();
    if (t < 64) red[0][t] = (red[0][t] + red[1][t] + red[2][t] + red[3][t]) * inv;
    __syncthreads();
    if (t < 10) {
        float o = hb[t];
        #pragma unroll
        for (int d2 = 0; d2 < 64; ++d2) o = fmaf(red[0][d2], hw[t * 64 + d2], o);
        out[b * 10 + t] = o;
    }
}

extern "C" void kernel_launch(void* const* d_in, const int* in_sizes, int n_in,
                              void* d_out, int out_size, void* d_ws, size_t ws_size,
                              hipStream_t stream) {
    (void)in_sizes; (void)n_in; (void)out_size; (void)ws_size;
    const float* x    = (const float*)d_in[0];
    const float* role = (const float*)d_in[1];
    const float* fw   = (const float*)d_in[2];
    const float* qw   = (const float*)d_in[3];
    const float* qb   = (const float*)d_in[4];
    const float* kw   = (const float*)d_in[5];
    const float* kb   = (const float*)d_in[6];
    const float* vw   = (const float*)d_in[7];
    const float* vb   = (const float*)d_in[8];
    const float* w1   = (const float*)d_in[9];
    const float* b1   = (const float*)d_in[10];
    const float* w2   = (const float*)d_in[11];
    // d_in[12] = b2: softmax-shift-invariant, dropped
    const float* ow   = (const float*)d_in[13];
    const float* ob   = (const float*)d_in[14];
    const float* g1   = (const float*)d_in[15];
    const float* be1  = (const float*)d_in[16];
    const float* f1w  = (const float*)d_in[17];
    const float* f1b  = (const float*)d_in[18];
    const float* f2w  = (const float*)d_in[19];
    const float* f2b  = (const float*)d_in[20];
    const float* g2   = (const float*)d_in[21];
    const float* be2  = (const float*)d_in[22];
    const float* tq   = (const float*)d_in[23];
    const float* hw   = (const float*)d_in[24];
    const float* hb   = (const float*)d_in[25];

    float* ws   = (float*)d_ws;
    const size_t M = 1048576;                        // B*C*D
    float* H    = ws;
    float* Q    = ws + 1 * M;
    float* K    = ws + 2 * M;
    float* V    = ws + 3 * M;
    float* Abuf = ws + 4 * M;
    float* KP   = ws + 5 * M;
    float* AT   = ws + 6 * M;
    float* PACC = ws + 7 * M;                        // 4*32*2048*16 = 4M floats
    float* PS   = ws + 11 * M + 262144;              // 4*32*2048

    k_binding<<<4096, 256, 0, stream>>>(x, role, fw, H);
    for (int l = 0; l < LL; ++l) {
        k_qkv<<<4096, 256, 0, stream>>>(H, qw + l * 4096, qb + l * 64, kw + l * 4096, kb + l * 64,
                                        vw + l * 4096, vb + l * 64, w1 + l * 768, b1 + l * 16,
                                        Q, K, V, Abuf, KP);
        k_attn<<<1024, 256, 0, stream>>>(Q, K, V, Abuf, KP, w1 + l * 768, w2 + l * 16, PACC, PS);
        k_attn_combine<<<256, 256, 0, stream>>>(PACC, PS, AT);
        k_oproj_ln<<<4096, 256, 0, stream>>>(AT, ow + l * 4096, ob + l * 64, g1 + l * 64, be1 + l * 64, H);
        k_ffn_ln<<<16384, 256, 0, stream>>>(f1w + l * 16384, f1b + l * 256, f2w + l * 16384,
                                            f2b + l * 64, g2 + l * 64, be2 + l * 64, H);
    }
    k_readout<<<8, 256, 0, stream>>>(H, tq, hw, hb, (float*)d_out);
}